// Round 1
// baseline (915.312 us; speedup 1.0000x reference)
//
#include <hip/hip_runtime.h>
#include <hip/hip_bf16.h>

typedef _Float16 half_t;
typedef _Float16 half8 __attribute__((ext_vector_type(8)));
typedef _Float16 half4v __attribute__((ext_vector_type(4)));
typedef float floatx4 __attribute__((ext_vector_type(4)));

// ---------------- weight transpose + fp32->fp16: Wt[n][k] = W[k][n], N fixed = 1024 ----------------
__global__ __launch_bounds__(256) void wtrans_kernel(const float* __restrict__ W,
                                                     half_t* __restrict__ Wt, int K) {
  __shared__ float sm[32][33];
  int n0 = blockIdx.x * 32, k0 = blockIdx.y * 32;
  int x = threadIdx.x & 31, y0 = threadIdx.x >> 5;
#pragma unroll
  for (int yy = 0; yy < 4; ++yy) {
    int y = y0 + yy * 8;
    sm[y][x] = W[(size_t)(k0 + y) * 1024 + n0 + x];
  }
  __syncthreads();
#pragma unroll
  for (int yy = 0; yy < 4; ++yy) {
    int y = y0 + yy * 8;
    Wt[(size_t)(n0 + y) * K + k0 + x] = (half_t)sm[x][y];
  }
}

// ---------------- NT GEMM: C[m][n] = sum_k A[m][k]*Bt[n][k] (+bias[n]), fp16 MFMA, fp32 acc ----------------
// tile 128x128, BK=32, 256 threads = 4 waves in 2x2, each wave 64x64 via 4x4 of 16x16x32 MFMA.
// LDS tiles xor-swizzled (group g at g ^ ((row>>1)&3)) -> 2-way bank aliasing only (free).
template <bool AF32, bool BIAS>
__global__ __launch_bounds__(256) void gemm_nt(
    const float* __restrict__ Af, const half_t* __restrict__ Ah,
    const half_t* __restrict__ Bt, const float* __restrict__ bias,
    half_t* __restrict__ C, int K, int ldc,
    size_t aStrideZ, size_t bStrideZ, size_t cStrideZ) {
  __shared__ half_t sA[128 * 32];
  __shared__ half_t sB[128 * 32];
  const int t = threadIdx.x;
  const int m0 = blockIdx.x * 128;
  const int n0 = blockIdx.y * 128;
  const int z = blockIdx.z;
  const half_t* Bz = Bt + bStrideZ * (size_t)z;
  const int w = t >> 6, lane = t & 63;
  const int wm = w & 1, wn = w >> 1;
  const int lr = lane & 15, lk = lane >> 4;
  const int srow = t >> 2, sg = t & 3;

  floatx4 acc[4][4] = {};

  for (int k0 = 0; k0 < K; k0 += 32) {
    __syncthreads();
#pragma unroll
    for (int rep = 0; rep < 2; ++rep) {
      int row = srow + rep * 64;
      int goff = (sg ^ ((row >> 1) & 3)) * 8;
      half8 hv;
      if constexpr (AF32) {
        const float* p = Af + (size_t)(m0 + row) * K + k0 + sg * 8;
        float4 f0 = *(const float4*)p;
        float4 f1 = *(const float4*)(p + 4);
        hv[0] = (half_t)f0.x; hv[1] = (half_t)f0.y;
        hv[2] = (half_t)f0.z; hv[3] = (half_t)f0.w;
        hv[4] = (half_t)f1.x; hv[5] = (half_t)f1.y;
        hv[6] = (half_t)f1.z; hv[7] = (half_t)f1.w;
      } else {
        const half_t* p = Ah + aStrideZ * (size_t)z + (size_t)(m0 + row) * K + k0 + sg * 8;
        hv = *(const half8*)p;
      }
      *(half8*)&sA[row * 32 + goff] = hv;
      const half_t* q = Bz + (size_t)(n0 + row) * K + k0 + sg * 8;
      *(half8*)&sB[row * 32 + goff] = *(const half8*)q;
    }
    __syncthreads();
    half8 af[4], bf[4];
#pragma unroll
    for (int mt = 0; mt < 4; ++mt) {
      int row = wm * 64 + mt * 16 + lr;
      af[mt] = *(const half8*)&sA[row * 32 + ((lk ^ ((row >> 1) & 3)) * 8)];
    }
#pragma unroll
    for (int nt = 0; nt < 4; ++nt) {
      int row = wn * 64 + nt * 16 + lr;
      bf[nt] = *(const half8*)&sB[row * 32 + ((lk ^ ((row >> 1) & 3)) * 8)];
    }
#pragma unroll
    for (int mt = 0; mt < 4; ++mt)
#pragma unroll
      for (int nt = 0; nt < 4; ++nt)
        acc[mt][nt] = __builtin_amdgcn_mfma_f32_16x16x32_f16(af[mt], bf[nt], acc[mt][nt], 0, 0, 0);
  }

  half_t* Cz = C + cStrideZ * (size_t)z;
#pragma unroll
  for (int nt = 0; nt < 4; ++nt) {
    int n = n0 + wn * 64 + nt * 16 + lr;
    float bval = 0.0f;
    if constexpr (BIAS) bval = bias[n];
#pragma unroll
    for (int mt = 0; mt < 4; ++mt) {
      int mbase = m0 + wm * 64 + mt * 16 + lk * 4;
#pragma unroll
      for (int i = 0; i < 4; ++i) {
        float v = acc[mt][nt][i] + bval;
        Cz[(size_t)(mbase + i) * ldc + n] = (half_t)v;
      }
    }
  }
}

// ---------------- in-place row softmax: reads fp16 scores from row slot, writes fp32 attn ----------------
__global__ __launch_bounds__(256) void softmax_kernel(float* __restrict__ attnRegion) {
  size_t row = blockIdx.x;
  float* rowp = attnRegion + row * 1024;
  const half_t* src = (const half_t*)rowp;
  int t = threadIdx.x;
  half4v h = *(const half4v*)(src + t * 4);
  float e0 = __expf((float)h[0]);
  float e1 = __expf((float)h[1]);
  float e2 = __expf((float)h[2]);
  float e3 = __expf((float)h[3]);
  float s = (e0 + e1) + (e2 + e3);
#pragma unroll
  for (int off = 32; off > 0; off >>= 1) s += __shfl_xor(s, off);
  __shared__ float sm[4];
  if ((t & 63) == 0) sm[t >> 6] = s;
  __syncthreads();  // also guarantees all fp16 reads complete before fp32 overwrite
  float rl = 1.0f / (sm[0] + sm[1] + sm[2] + sm[3]);
  float4 o;
  o.x = e0 * rl; o.y = e1 * rl; o.z = e2 * rl; o.w = e3 * rl;
  *(float4*)(rowp + t * 4) = o;
}

// ---------------- column sums of attn grouped by (q mod 4): cs[bh][r][k] ----------------
__global__ __launch_bounds__(256) void cs_kernel(const float* __restrict__ attn, float* __restrict__ cs) {
  int bh = blockIdx.x, kc = blockIdx.y;
  int t = threadIdx.x;
  int col = kc * 128 + (t & 127);
  int hf = t >> 7;
  const float* base = attn + (size_t)bh * 1048576 + col;
  float a0 = 0, a1 = 0, a2 = 0, a3 = 0;
  int q0 = hf * 512;
  for (int q = q0; q < q0 + 512; q += 4) {
    a0 += base[(size_t)q * 1024];
    a1 += base[(size_t)(q + 1) * 1024];
    a2 += base[(size_t)(q + 2) * 1024];
    a3 += base[(size_t)(q + 3) * 1024];
  }
  __shared__ float sm[2][4][128];
  int c = t & 127;
  sm[hf][0][c] = a0; sm[hf][1][c] = a1; sm[hf][2][c] = a2; sm[hf][3][c] = a3;
  __syncthreads();
  if (t < 128) {
#pragma unroll
    for (int i = 0; i < 4; ++i)
      cs[(size_t)bh * 4096 + (size_t)i * 1024 + kc * 128 + t] = sm[0][i][t] + sm[1][i][t];
  }
}

// ---------------- abar[b, r*256+d] = (1/1024) sum_{h,k} cs[bh][r][k] * Tv[bh][k][d] ----------------
__global__ __launch_bounds__(256) void abar_kernel(const float* __restrict__ cs,
                                                   const half_t* __restrict__ Tv,
                                                   float* __restrict__ abar) {
  int b = blockIdx.x, r = blockIdx.y, kc = blockIdx.z;
  int d = threadIdx.x;
  __shared__ float scs[4][128];
  for (int idx = d; idx < 512; idx += 256) {
    int h = idx >> 7, k = idx & 127;
    scs[h][k] = cs[(size_t)(b * 4 + h) * 4096 + (size_t)r * 1024 + kc * 128 + k];
  }
  __syncthreads();
  float acc = 0.0f;
  for (int h = 0; h < 4; ++h) {
    const half_t* tv = Tv + (size_t)(b * 4 + h) * 262144 + (size_t)kc * 32768 + d;
#pragma unroll 4
    for (int k = 0; k < 128; ++k)
      acc += scs[h][k] * (float)tv[(size_t)k * 256];
  }
  atomicAdd(&abar[b * 1024 + r * 256 + d], acc * (1.0f / 1024.0f));
}

// ---------------- out[b] = (abar[b] @ Wo + bo) @ W1 + b1 ----------------
__global__ __launch_bounds__(256) void final_kernel(const float* __restrict__ abar,
                                                    const float* __restrict__ Wo,
                                                    const float* __restrict__ bo,
                                                    const float* __restrict__ W1,
                                                    const float* __restrict__ b1,
                                                    float* __restrict__ out) {
  int b = blockIdx.x, t = threadIdx.x;
  __shared__ float sa[1024];
  __shared__ float stmp[2048];
  for (int i = t; i < 1024; i += 256) sa[i] = abar[(size_t)b * 1024 + i];
  __syncthreads();
  int j0 = t * 8;
  float accv[8];
#pragma unroll
  for (int i = 0; i < 8; ++i) accv[i] = bo[j0 + i];
  for (int c = 0; c < 1024; ++c) {
    float av = sa[c];
    const float* wrow = Wo + (size_t)c * 2048 + j0;
#pragma unroll
    for (int i = 0; i < 8; ++i) accv[i] += av * wrow[i];
  }
#pragma unroll
  for (int i = 0; i < 8; ++i) stmp[j0 + i] = accv[i];
  __syncthreads();
  if (t < 128) {
    float acc = b1[t];
    for (int j = 0; j < 2048; ++j) acc += stmp[j] * W1[(size_t)j * 128 + t];
    out[(size_t)b * 128 + t] = acc;
  }
}

extern "C" void kernel_launch(void* const* d_in, const int* in_sizes, int n_in,
                              void* d_out, int out_size, void* d_ws, size_t ws_size,
                              hipStream_t stream) {
  const float* query = (const float*)d_in[0];
  const float* key   = (const float*)d_in[1];
  const float* value = (const float*)d_in[2];
  const float* Wq = (const float*)d_in[3];
  const float* bq = (const float*)d_in[4];
  const float* Wk = (const float*)d_in[5];
  const float* bk = (const float*)d_in[6];
  const float* Wv = (const float*)d_in[7];
  const float* bv = (const float*)d_in[8];
  const float* Wo = (const float*)d_in[9];
  const float* bo = (const float*)d_in[10];
  const float* W1 = (const float*)d_in[11];
  const float* b1 = (const float*)d_in[12];

  // workspace layout (bytes), total ~98.3 MB
  char* ws = (char*)d_ws;
  half_t* Tq   = (half_t*)(ws + 0);          // 16M halves  [b][s][1024]
  half_t* Tk   = (half_t*)(ws + 33554432);   // 16M halves
  half_t* Tv   = (half_t*)(ws + 67108864);   // 16M halves
  float*  cs   = (float*)(ws + 100663296);   // [64][4][1024] f32
  float*  abar = (float*)(ws + 101711872);   // [16][1024] f32
  half_t* Wqt  = (half_t*)(ws + 101777408);  // [1024][128] f16
  half_t* Wkt  = (half_t*)(ws + 102039552);  // [1024][256] f16
  half_t* Wvt  = (half_t*)(ws + 102563840);  // [1024][256] f16

  float* out  = (float*)d_out;
  float* attn = out + 2048;  // [64][1024][1024] f32

  hipMemsetAsync(cs, 0, 1048576 + 65536, stream);  // zero cs + abar

  wtrans_kernel<<<dim3(32, 4), 256, 0, stream>>>(Wq, Wqt, 128);
  wtrans_kernel<<<dim3(32, 8), 256, 0, stream>>>(Wk, Wkt, 256);
  wtrans_kernel<<<dim3(32, 8), 256, 0, stream>>>(Wv, Wvt, 256);

  // projections: T = X @ W + b  (fp32 A staged->fp16, fp16 out)
  gemm_nt<true, true><<<dim3(128, 8, 1), 256, 0, stream>>>(query, nullptr, Wqt, bq, Tq, 128, 1024, 0, 0, 0);
  gemm_nt<true, true><<<dim3(128, 8, 1), 256, 0, stream>>>(key,   nullptr, Wkt, bk, Tk, 256, 1024, 0, 0, 0);
  gemm_nt<true, true><<<dim3(128, 8, 1), 256, 0, stream>>>(value, nullptr, Wvt, bv, Tv, 256, 1024, 0, 0, 0);

  // scores per head: Tq_h [1024,256] @ Tk_h^T -> fp16 written into attn rows (first 2048 B of each 4096 B slot)
  gemm_nt<false, false><<<dim3(8, 8, 64), 256, 0, stream>>>(nullptr, Tq, Tk, nullptr,
      (half_t*)attn, 256, 2048, 262144, 262144, (size_t)1024 * 2048);

  softmax_kernel<<<65536, 256, 0, stream>>>(attn);           // in-place fp16 scores -> fp32 attn
  cs_kernel<<<dim3(64, 8), 256, 0, stream>>>(attn, cs);       // attn column sums by q%4
  abar_kernel<<<dim3(16, 4, 8), 256, 0, stream>>>(cs, Tv, abar);
  final_kernel<<<16, 256, 0, stream>>>(abar, Wo, bo, W1, b1, out);
}

// Round 2
// 733.940 us; speedup vs baseline: 1.2471x; 1.2471x over previous
//
#include <hip/hip_runtime.h>
#include <hip/hip_bf16.h>

typedef _Float16 half_t;
typedef _Float16 half8 __attribute__((ext_vector_type(8)));
typedef _Float16 half4v __attribute__((ext_vector_type(4)));
typedef float floatx4 __attribute__((ext_vector_type(4)));

// ---------------- weight transpose + fp32->fp16: Wt[n][k] = W[k][n], W is [K][N] ----------------
__global__ __launch_bounds__(256) void wtrans_kernel(const float* __restrict__ W,
                                                     half_t* __restrict__ Wt, int K, int N) {
  __shared__ float sm[32][33];
  int n0 = blockIdx.x * 32, k0 = blockIdx.y * 32;
  int x = threadIdx.x & 31, y0 = threadIdx.x >> 5;
#pragma unroll
  for (int yy = 0; yy < 4; ++yy) {
    int y = y0 + yy * 8;
    sm[y][x] = W[(size_t)(k0 + y) * N + n0 + x];
  }
  __syncthreads();
#pragma unroll
  for (int yy = 0; yy < 4; ++yy) {
    int y = y0 + yy * 8;
    Wt[(size_t)(n0 + y) * K + k0 + x] = (half_t)sm[x][y];
  }
}

// ---------------- NT GEMM: C[m][n] = sum_k A[m][k]*Bt[n][k] (+bias[n]), fp16 MFMA, fp32 acc ----------------
// tile 128x128, BK=32, 256 threads = 4 waves in 2x2, each wave 64x64 via 4x4 of 16x16x32 MFMA.
// MFMA operands SWAPPED (mfma(bf, af)): lane then owns 4 consecutive n of one row m
// -> half4 (8B) C-stores, 32B-contiguous per output row. Numerically identical.
template <bool AF32, bool BIAS>
__global__ __launch_bounds__(256) void gemm_nt(
    const float* __restrict__ Af, const half_t* __restrict__ Ah,
    const half_t* __restrict__ Bt, const float* __restrict__ bias,
    half_t* __restrict__ C, int K, int ldc,
    size_t aStrideZ, size_t bStrideZ, size_t cStrideZ) {
  __shared__ half_t sA[128 * 32];
  __shared__ half_t sB[128 * 32];
  const int t = threadIdx.x;
  const int m0 = blockIdx.x * 128;
  const int n0 = blockIdx.y * 128;
  const int z = blockIdx.z;
  const half_t* Bz = Bt + bStrideZ * (size_t)z;
  const int w = t >> 6, lane = t & 63;
  const int wm = w & 1, wn = w >> 1;
  const int lr = lane & 15, lk = lane >> 4;
  const int srow = t >> 2, sg = t & 3;

  floatx4 acc[4][4] = {};

  for (int k0 = 0; k0 < K; k0 += 32) {
    __syncthreads();
#pragma unroll
    for (int rep = 0; rep < 2; ++rep) {
      int row = srow + rep * 64;
      int goff = (sg ^ ((row >> 1) & 3)) * 8;
      half8 hv;
      if constexpr (AF32) {
        const float* p = Af + (size_t)(m0 + row) * K + k0 + sg * 8;
        float4 f0 = *(const float4*)p;
        float4 f1 = *(const float4*)(p + 4);
        hv[0] = (half_t)f0.x; hv[1] = (half_t)f0.y;
        hv[2] = (half_t)f0.z; hv[3] = (half_t)f0.w;
        hv[4] = (half_t)f1.x; hv[5] = (half_t)f1.y;
        hv[6] = (half_t)f1.z; hv[7] = (half_t)f1.w;
      } else {
        const half_t* p = Ah + aStrideZ * (size_t)z + (size_t)(m0 + row) * K + k0 + sg * 8;
        hv = *(const half8*)p;
      }
      *(half8*)&sA[row * 32 + goff] = hv;
      const half_t* q = Bz + (size_t)(n0 + row) * K + k0 + sg * 8;
      *(half8*)&sB[row * 32 + goff] = *(const half8*)q;
    }
    __syncthreads();
    half8 af[4], bf[4];
#pragma unroll
    for (int mt = 0; mt < 4; ++mt) {
      int row = wm * 64 + mt * 16 + lr;
      af[mt] = *(const half8*)&sA[row * 32 + ((lk ^ ((row >> 1) & 3)) * 8)];
    }
#pragma unroll
    for (int nt = 0; nt < 4; ++nt) {
      int row = wn * 64 + nt * 16 + lr;
      bf[nt] = *(const half8*)&sB[row * 32 + ((lk ^ ((row >> 1) & 3)) * 8)];
    }
#pragma unroll
    for (int mt = 0; mt < 4; ++mt)
#pragma unroll
      for (int nt = 0; nt < 4; ++nt)
        acc[mt][nt] = __builtin_amdgcn_mfma_f32_16x16x32_f16(bf[nt], af[mt], acc[mt][nt], 0, 0, 0);
  }

  // swapped layout: m = ...+lr (lane&15), n = ...+lk*4+i ((lane>>4)*4+reg)
  half_t* Cz = C + cStrideZ * (size_t)z;
#pragma unroll
  for (int mt = 0; mt < 4; ++mt) {
    int m = m0 + wm * 64 + mt * 16 + lr;
#pragma unroll
    for (int nt = 0; nt < 4; ++nt) {
      int nb = n0 + wn * 64 + nt * 16 + lk * 4;
      floatx4 a = acc[mt][nt];
      half4v h;
      if constexpr (BIAS) {
        float4 bv = *(const float4*)&bias[nb];
        h[0] = (half_t)(a[0] + bv.x); h[1] = (half_t)(a[1] + bv.y);
        h[2] = (half_t)(a[2] + bv.z); h[3] = (half_t)(a[3] + bv.w);
      } else {
        h[0] = (half_t)a[0]; h[1] = (half_t)a[1];
        h[2] = (half_t)a[2]; h[3] = (half_t)a[3];
      }
      *(half4v*)&Cz[(size_t)m * ldc + nb] = h;
    }
  }
}

// ---------------- fused softmax + column-sums ----------------
// grid (64 bh, 16 slices), 256 thr. Wave w handles rows q%4==w of its 64-row slice,
// so per-wave column sums for cs[bh][w][*] live in 16 VGPRs; one atomicAdd set at end.
// Reads fp16 scores in-place from attn row slots, writes fp32 attn.
__global__ __launch_bounds__(256) void softcs_kernel(float* __restrict__ attn,
                                                     float* __restrict__ cs) {
  int bh = blockIdx.x, slice = blockIdx.y;
  int t = threadIdx.x;
  int w = t >> 6, lane = t & 63;
  float csacc[16];
#pragma unroll
  for (int j = 0; j < 16; ++j) csacc[j] = 0.0f;

  for (int i = 0; i < 16; ++i) {
    int q = slice * 64 + i * 4 + w;
    float* rowp = attn + ((size_t)bh * 1024 + q) * 1024;
    const half_t* sh = (const half_t*)rowp;
    float ex[16];
    float s = 0.0f;
#pragma unroll
    for (int c = 0; c < 4; ++c) {
      half4v h = *(const half4v*)(sh + c * 256 + lane * 4);
#pragma unroll
      for (int j = 0; j < 4; ++j) {
        float e = __expf((float)h[j]);
        ex[c * 4 + j] = e;
        s += e;
      }
    }
#pragma unroll
    for (int off = 1; off < 64; off <<= 1) s += __shfl_xor(s, off);
    float rl = 1.0f / s;
#pragma unroll
    for (int c = 0; c < 4; ++c) {
      float4 o;
      o.x = ex[c * 4 + 0] * rl; o.y = ex[c * 4 + 1] * rl;
      o.z = ex[c * 4 + 2] * rl; o.w = ex[c * 4 + 3] * rl;
      *(float4*)(rowp + c * 256 + lane * 4) = o;
      csacc[c * 4 + 0] += o.x; csacc[c * 4 + 1] += o.y;
      csacc[c * 4 + 2] += o.z; csacc[c * 4 + 3] += o.w;
    }
  }
  float* csp = cs + (size_t)bh * 4096 + (size_t)w * 1024 + lane * 4;
#pragma unroll
  for (int c = 0; c < 4; ++c)
#pragma unroll
    for (int j = 0; j < 4; ++j)
      atomicAdd(csp + c * 256 + j, csacc[c * 4 + j]);
}

// ---------------- abar[b, r*256+d] = (1/1024) sum_{h,k} cs[bh][r][k] * Tv[bh][k][d] ----------------
__global__ __launch_bounds__(256) void abar_kernel(const float* __restrict__ cs,
                                                   const half_t* __restrict__ Tv,
                                                   float* __restrict__ abar) {
  int b = blockIdx.x, r = blockIdx.y, kc = blockIdx.z;
  int d = threadIdx.x;
  __shared__ float scs[4][128];
  for (int idx = d; idx < 512; idx += 256) {
    int h = idx >> 7, k = idx & 127;
    scs[h][k] = cs[(size_t)(b * 4 + h) * 4096 + (size_t)r * 1024 + kc * 128 + k];
  }
  __syncthreads();
  float acc = 0.0f;
  for (int h = 0; h < 4; ++h) {
    const half_t* tv = Tv + (size_t)(b * 4 + h) * 262144 + (size_t)kc * 32768 + d;
#pragma unroll 4
    for (int k = 0; k < 128; ++k)
      acc += scs[h][k] * (float)tv[(size_t)k * 256];
  }
  atomicAdd(&abar[b * 1024 + r * 256 + d], acc * (1.0f / 1024.0f));
}

// ---------------- bcomb[j] = b1[j] + sum_k bo[k] * W1[k][j] ----------------
__global__ __launch_bounds__(256) void bcomb_kernel(const float* __restrict__ bo,
                                                    const float* __restrict__ W1,
                                                    const float* __restrict__ b1,
                                                    float* __restrict__ bcomb) {
  int t = threadIdx.x;
  int j = t & 127, h = t >> 7;
  float acc = 0.0f;
  for (int k = h * 1024; k < h * 1024 + 1024; ++k)
    acc += bo[k] * W1[(size_t)k * 128 + j];
  __shared__ float sm[2][128];
  sm[h][j] = acc;
  __syncthreads();
  if (t < 128) bcomb[t] = sm[0][t] + sm[1][t] + b1[t];
}

// ---------------- out[b][j] = bcomb[j] + sum_c abar[b][c] * Wcomb[c][j] ----------------
__global__ __launch_bounds__(256) void final2_kernel(const float* __restrict__ abar,
                                                     const half_t* __restrict__ Wcomb,
                                                     const float* __restrict__ bcomb,
                                                     float* __restrict__ out) {
  int b = blockIdx.x, t = threadIdx.x;
  int j = t & 127, h = t >> 7;
  __shared__ float sa[1024];
  __shared__ float sm[2][128];
  for (int i = t; i < 1024; i += 256) sa[i] = abar[(size_t)b * 1024 + i];
  __syncthreads();
  float acc = 0.0f;
  for (int c = h * 512; c < h * 512 + 512; ++c)
    acc += sa[c] * (float)Wcomb[(size_t)c * 128 + j];
  sm[h][j] = acc;
  __syncthreads();
  if (t < 128) out[(size_t)b * 128 + t] = sm[0][t] + sm[1][t] + bcomb[t];
}

extern "C" void kernel_launch(void* const* d_in, const int* in_sizes, int n_in,
                              void* d_out, int out_size, void* d_ws, size_t ws_size,
                              hipStream_t stream) {
  const float* query = (const float*)d_in[0];
  const float* key   = (const float*)d_in[1];
  const float* value = (const float*)d_in[2];
  const float* Wq = (const float*)d_in[3];
  const float* bq = (const float*)d_in[4];
  const float* Wk = (const float*)d_in[5];
  const float* bk = (const float*)d_in[6];
  const float* Wv = (const float*)d_in[7];
  const float* bv = (const float*)d_in[8];
  const float* Wo = (const float*)d_in[9];
  const float* bo = (const float*)d_in[10];
  const float* W1 = (const float*)d_in[11];
  const float* b1 = (const float*)d_in[12];

  // workspace layout (bytes)
  char* ws = (char*)d_ws;
  half_t* Tq   = (half_t*)(ws + 0);          // 16M halves  [b][s][1024]  (dead after scores gemm)
  half_t* Tk   = (half_t*)(ws + 33554432);   // 16M halves
  half_t* Tv   = (half_t*)(ws + 67108864);   // 16M halves  (live until abar)
  float*  cs   = (float*)(ws + 100663296);   // [64][4][1024] f32
  float*  abar = (float*)(ws + 101711872);   // [16][1024] f32
  half_t* Wqt  = (half_t*)(ws + 101777408);  // [1024][128] f16
  half_t* Wkt  = (half_t*)(ws + 102039552);  // [1024][256] f16
  half_t* Wvt  = (half_t*)(ws + 102563840);  // [1024][256] f16
  // overlapped onto dead Tq region (only used after scores gemm):
  half_t* W1t   = (half_t*)(ws + 0);         // [128][2048] f16
  half_t* Wcomb = (half_t*)(ws + 524288);    // [1024][128] f16
  float*  bcomb = (float*)(ws + 786432);     // [128] f32

  float* out  = (float*)d_out;
  float* attn = out + 2048;  // [64][1024][1024] f32

  hipMemsetAsync(cs, 0, 1048576 + 65536, stream);  // zero cs + abar

  wtrans_kernel<<<dim3(32, 4), 256, 0, stream>>>(Wq, Wqt, 128, 1024);
  wtrans_kernel<<<dim3(32, 8), 256, 0, stream>>>(Wk, Wkt, 256, 1024);
  wtrans_kernel<<<dim3(32, 8), 256, 0, stream>>>(Wv, Wvt, 256, 1024);

  // projections: T = X @ W + b  (fp32 A staged->fp16, fp16 out)
  gemm_nt<true, true><<<dim3(128, 8, 1), 256, 0, stream>>>(query, nullptr, Wqt, bq, Tq, 128, 1024, 0, 0, 0);
  gemm_nt<true, true><<<dim3(128, 8, 1), 256, 0, stream>>>(key,   nullptr, Wkt, bk, Tk, 256, 1024, 0, 0, 0);
  gemm_nt<true, true><<<dim3(128, 8, 1), 256, 0, stream>>>(value, nullptr, Wvt, bv, Tv, 256, 1024, 0, 0, 0);

  // scores per head: Tq_h [1024,256] @ Tk_h^T -> fp16 into attn row slots (first 2048 B of 4096 B)
  gemm_nt<false, false><<<dim3(8, 8, 64), 256, 0, stream>>>(nullptr, Tq, Tk, nullptr,
      (half_t*)attn, 256, 2048, 262144, 262144, (size_t)1024 * 2048);

  // Wcomb = Wo @ W1 (folded tail GEMM), bcomb = bo @ W1 + b1 -- Tq region is dead now
  wtrans_kernel<<<dim3(4, 64), 256, 0, stream>>>(W1, W1t, 2048, 128);
  gemm_nt<true, false><<<dim3(8, 1, 1), 256, 0, stream>>>(Wo, nullptr, W1t, nullptr, Wcomb, 2048, 128, 0, 0, 0);
  bcomb_kernel<<<1, 256, 0, stream>>>(bo, W1, b1, bcomb);

  softcs_kernel<<<dim3(64, 16), 256, 0, stream>>>(attn, cs);   // fp16 scores -> fp32 attn + col sums
  abar_kernel<<<dim3(16, 4, 8), 256, 0, stream>>>(cs, Tv, abar);
  final2_kernel<<<16, 256, 0, stream>>>(abar, Wcomb, bcomb, out);
}